// Round 8
// baseline (746.357 us; speedup 1.0000x reference)
//
#include <hip/hip_runtime.h>
#include <hip/hip_bf16.h>

// Problem constants (fixed by setup_inputs)
#define TT    2209          // 47*47 relative-position table entries
#define NB    32            // batch
#define NH    16            // heads
#define ND    512           // RPB hidden dim
#define WH    24            // window height/width
#define NW    576           // 24*24 window tokens
#define NP    577           // NW + num_prefix_tokens(=1)
#define PLANE (NP * NP)     // 332929 floats per (b,h) output plane

// native clang vector type — required by __builtin_nontemporal_store
typedef float vfloat4 __attribute__((ext_vector_type(4)));

// a(t) = (t/24)*47 + t%24 = t + 23*(t/24);  t/24 == (t*2731)>>16 exactly for t < 1500
__device__ __forceinline__ unsigned a_of(unsigned t) {
    return t + 23u * ((t * 2731u) >> 16);
}

// ---------------------------------------------------------------------------
// Stage 1: bias_t[b][h][t] = (relu((coords_table[t] + pos[b]) @ W1 + b1) @ W2)[h]
// Weights staged in LDS; all weight reads are wave-uniform broadcasts
// (conflict-free). Head-major output so stage 2's gathers for one plane are
// one contiguous 8.8 KB block.  ~20 µs, LDS-issue/latency bound.
// ---------------------------------------------------------------------------
__global__ __launch_bounds__(256) void cpb_mlp(
    const float* __restrict__ glob_pos,     // (1, 32, 4)
    const float* __restrict__ coords_table, // (2209, 2)
    const float* __restrict__ W1,           // (2, 512)
    const float* __restrict__ b1,           // (512,)
    const float* __restrict__ W2,           // (512, 16)
    float* __restrict__ bias_t)             // (32, 16, 2209) scratch
{
    __shared__ float sW13[ND][4];           // {W1row0, W1row1, b1, pad} — 8 KB
    __shared__ float sW2[ND][NH];           // 32 KB

    const int tid = threadIdx.x;
    for (int d = tid; d < ND; d += 256) {
        float4 v;
        v.x = W1[d];            // W1[0][d]
        v.y = W1[ND + d];       // W1[1][d]
        v.z = b1[d];
        v.w = 0.0f;
        *reinterpret_cast<float4*>(&sW13[d][0]) = v;
    }
    for (int i = tid; i < ND * NH / 4; i += 256) {
        reinterpret_cast<float4*>(&sW2[0][0])[i] =
            reinterpret_cast<const float4*>(W2)[i];
    }
    __syncthreads();

    const unsigned gid  = blockIdx.x * 256u + tid;
    const bool     live = gid < (unsigned)(NB * TT);
    const unsigned b    = live ? gid / TT : 0u;
    const unsigned t    = live ? gid - b * TT : 0u;

    const float g0 = glob_pos[b * 4 + 0];
    const float g1 = glob_pos[b * 4 + 1];
    const float g2 = glob_pos[b * 4 + 2];
    const float g3 = glob_pos[b * 4 + 3];
    float px = g2 / g0 * 8.0f;
    float py = g3 / g1 * 8.0f;
    px = copysignf(log2f(fabsf(px) + 1.0f) * (1.0f / 3.0f), px) * 2.0f - 1.0f;
    py = copysignf(log2f(fabsf(py) + 1.0f) * (1.0f / 3.0f), py) * 2.0f - 1.0f;

    const float tx = coords_table[t * 2 + 0] + px;
    const float ty = coords_table[t * 2 + 1] + py;

    float acc[NH];
#pragma unroll
    for (int h = 0; h < NH; ++h) acc[h] = 0.0f;

#pragma unroll 1
    for (int d0 = 0; d0 < ND; d0 += 4) {
        float hv[4];
#pragma unroll
        for (int k = 0; k < 4; ++k) {
            const float4 w = *reinterpret_cast<const float4*>(&sW13[d0 + k][0]);
            hv[k] = fmaxf(fmaf(tx, w.x, fmaf(ty, w.y, w.z)), 0.0f);
        }
#pragma unroll
        for (int k = 0; k < 4; ++k) {
            const float4 w0 = *reinterpret_cast<const float4*>(&sW2[d0 + k][0]);
            const float4 w1 = *reinterpret_cast<const float4*>(&sW2[d0 + k][4]);
            const float4 w2 = *reinterpret_cast<const float4*>(&sW2[d0 + k][8]);
            const float4 w3 = *reinterpret_cast<const float4*>(&sW2[d0 + k][12]);
            acc[0]  = fmaf(hv[k], w0.x, acc[0]);   acc[1]  = fmaf(hv[k], w0.y, acc[1]);
            acc[2]  = fmaf(hv[k], w0.z, acc[2]);   acc[3]  = fmaf(hv[k], w0.w, acc[3]);
            acc[4]  = fmaf(hv[k], w1.x, acc[4]);   acc[5]  = fmaf(hv[k], w1.y, acc[5]);
            acc[6]  = fmaf(hv[k], w1.z, acc[6]);   acc[7]  = fmaf(hv[k], w1.w, acc[7]);
            acc[8]  = fmaf(hv[k], w2.x, acc[8]);   acc[9]  = fmaf(hv[k], w2.y, acc[9]);
            acc[10] = fmaf(hv[k], w2.z, acc[10]);  acc[11] = fmaf(hv[k], w2.w, acc[11]);
            acc[12] = fmaf(hv[k], w3.x, acc[12]);  acc[13] = fmaf(hv[k], w3.y, acc[13]);
            acc[14] = fmaf(hv[k], w3.z, acc[14]);  acc[15] = fmaf(hv[k], w3.w, acc[15]);
        }
    }

    if (live) {
#pragma unroll
        for (int h = 0; h < NH; ++h) {
            bias_t[(b * NH + h) * TT + t] = acc[h];
        }
    }
}

// ---------------------------------------------------------------------------
// Stage 2: out[flat] — float4 nontemporal store stream with incremental
// (i, j, soff, base_i) state.  idx = 1104 + a(i-1) - a(j-1), a(t) = t + 23*(t/24),
// t/24 via exact (t*2731)>>16 — no v_mul_hi chains, no per-element divides.
// All LDS gather indices provably in [0, 2*TT) so masked lanes read safely.
// ---------------------------------------------------------------------------
#define VPT   41u                       // float4 groups per thread
#define EPB   (256u * VPT * 4u)         // elements per block = 41984 (< PLANE)

__global__ __launch_bounds__(256) void cpb_scatter(
    const float* __restrict__ bias_t, // (32, 16, 2209)
    float* __restrict__ out)          // (32, 16, 577, 577) flat
{
    constexpr unsigned TOTAL = (unsigned)NB * NH * PLANE; // 170,459,648 (div 4)

    const unsigned bx    = blockIdx.x;
    const unsigned tid   = threadIdx.x;
    const unsigned ebase = bx * EPB;
    if (ebase >= TOTAL) return;                 // whole block OOB (uniform)

    __shared__ float sAB[2 * TT];               // first & last plane this block touches

    const unsigned eend = min(ebase + EPB, TOTAL);
    const unsigned pA   = ebase / PLANE;
    const unsigned pB   = (eend - 1u) / PLANE;  // pA or pA+1, <= 511
    const float* __restrict__ plA = bias_t + (size_t)pA * TT;
    const float* __restrict__ plB = bias_t + (size_t)pB * TT;
    for (unsigned x = tid; x < (unsigned)TT; x += 256u) {
        sAB[x]      = plA[x];
        sAB[TT + x] = plB[x];
    }
    __syncthreads();

    // --- per-thread incremental state for its first element ---
    unsigned off = ebase + tid * 4u;            // flat element index
    unsigned p0  = off / PLANE;                 // magic-mul, once
    unsigned rem = off - p0 * PLANE;
    unsigned i   = rem / NP;                    // magic-mul, once
    unsigned j   = rem - i * NP;
    unsigned soff   = (p0 > pA) ? (unsigned)TT : 0u;
    unsigned base_i = 1104u + a_of(i ? i - 1u : 0u);

#pragma unroll 2
    for (unsigned k = 0; k < VPT; ++k) {
        vfloat4 o;
#pragma unroll
        for (int d = 0; d < 4; ++d) {
            const unsigned tj  = j ? j - 1u : 0u;
            const unsigned idx = soff + base_i - a_of(tj);   // in [0, 2*TT)
            const float    v   = sAB[idx];
            o[d] = (i != 0u && j != 0u) ? v : 0.0f;
            // advance by one element
            if (++j == (unsigned)NP) {
                j = 0u;
                if (++i == (unsigned)NP) { i = 0u; soff = (unsigned)TT; }
                base_i = 1104u + a_of(i ? i - 1u : 0u);
            }
        }
        if (off < TOTAL) {
            __builtin_nontemporal_store(o, reinterpret_cast<vfloat4*>(out + off));
        }
        // advance to next iteration's first element: +1020 (total +1024)
        j += 1020u;
        if (j >= (unsigned)NP) { j -= (unsigned)NP; ++i; }
        if (j >= (unsigned)NP) { j -= (unsigned)NP; ++i; }
        if (i >= (unsigned)NP) { i -= (unsigned)NP; soff = (unsigned)TT; }
        base_i = 1104u + a_of(i ? i - 1u : 0u);
        off += 1024u;
    }
}

// ---------------------------------------------------------------------------
extern "C" void kernel_launch(void* const* d_in, const int* in_sizes, int n_in,
                              void* d_out, int out_size, void* d_ws, size_t ws_size,
                              hipStream_t stream)
{
    const float* glob_pos     = (const float*)d_in[0];
    const float* coords_table = (const float*)d_in[1];
    // d_in[2] = rpi — unused (index computed analytically in stage 2)
    const float* W1           = (const float*)d_in[3];
    const float* b1           = (const float*)d_in[4];
    const float* W2           = (const float*)d_in[5];
    // d_in[6] = num_prefix_tokens (always 1; NP/PLANE are compile-time)

    float* out    = (float*)d_out;
    float* bias_t = (float*)d_ws;   // 32*16*2209 floats = 4.5 MB scratch

    // Stage 1: 32*2209 = 70,688 threads
    const int n1 = NB * TT;
    const int blocks1 = (n1 + 255) / 256;
    cpb_mlp<<<blocks1, 256, 0, stream>>>(glob_pos, coords_table, W1, b1, W2, bias_t);

    // Stage 2: contiguous flat ranges, 41,984 elems / block
    constexpr unsigned TOTAL  = (unsigned)NB * NH * PLANE;
    const unsigned blocks2 = (TOTAL + EPB - 1u) / EPB;   // 4061
    cpb_scatter<<<blocks2, 256, 0, stream>>>(bias_t, out);
}

// Round 11
// 733.048 us; speedup vs baseline: 1.0182x; 1.0182x over previous
//
#include <hip/hip_runtime.h>
#include <hip/hip_bf16.h>

// Problem constants (fixed by setup_inputs)
#define TT    2209          // 47*47 relative-position table entries
#define NB    32            // batch
#define NH    16            // heads
#define ND    512           // RPB hidden dim
#define WH    24            // window height/width
#define NW    576           // 24*24 window tokens
#define NP    577           // NW + num_prefix_tokens(=1)
#define PLANE (NP * NP)     // 332929 floats per (b,h) output plane

// ---------------------------------------------------------------------------
// Stage 1: bias_t[b][h][t] = (relu((coords_table[t] + pos[b]) @ W1 + b1) @ W2)[h]
// Weights staged in LDS; all weight reads are wave-uniform broadcasts
// (conflict-free). Head-major output so stage 2's gathers for one plane are
// one contiguous 8.8 KB block.
// ---------------------------------------------------------------------------
__global__ __launch_bounds__(256) void cpb_mlp(
    const float* __restrict__ glob_pos,     // (1, 32, 4)
    const float* __restrict__ coords_table, // (2209, 2)
    const float* __restrict__ W1,           // (2, 512)
    const float* __restrict__ b1,           // (512,)
    const float* __restrict__ W2,           // (512, 16)
    float* __restrict__ bias_t)             // (32, 16, 2209) scratch
{
    __shared__ float sW13[ND][4];           // {W1row0, W1row1, b1, pad} — 8 KB
    __shared__ float sW2[ND][NH];           // 32 KB

    const int tid = threadIdx.x;
    for (int d = tid; d < ND; d += 256) {
        float4 v;
        v.x = W1[d];            // W1[0][d]
        v.y = W1[ND + d];       // W1[1][d]
        v.z = b1[d];
        v.w = 0.0f;
        *reinterpret_cast<float4*>(&sW13[d][0]) = v;
    }
    for (int i = tid; i < ND * NH / 4; i += 256) {
        reinterpret_cast<float4*>(&sW2[0][0])[i] =
            reinterpret_cast<const float4*>(W2)[i];
    }
    __syncthreads();

    const unsigned gid  = blockIdx.x * 256u + tid;
    const bool     live = gid < (unsigned)(NB * TT);
    const unsigned b    = live ? gid / TT : 0u;
    const unsigned t    = live ? gid - b * TT : 0u;

    const float g0 = glob_pos[b * 4 + 0];
    const float g1 = glob_pos[b * 4 + 1];
    const float g2 = glob_pos[b * 4 + 2];
    const float g3 = glob_pos[b * 4 + 3];
    float px = g2 / g0 * 8.0f;
    float py = g3 / g1 * 8.0f;
    px = copysignf(log2f(fabsf(px) + 1.0f) * (1.0f / 3.0f), px) * 2.0f - 1.0f;
    py = copysignf(log2f(fabsf(py) + 1.0f) * (1.0f / 3.0f), py) * 2.0f - 1.0f;

    const float tx = coords_table[t * 2 + 0] + px;
    const float ty = coords_table[t * 2 + 1] + py;

    float acc[NH];
#pragma unroll
    for (int h = 0; h < NH; ++h) acc[h] = 0.0f;

#pragma unroll 1
    for (int d0 = 0; d0 < ND; d0 += 4) {
        float hv[4];
#pragma unroll
        for (int k = 0; k < 4; ++k) {
            const float4 w = *reinterpret_cast<const float4*>(&sW13[d0 + k][0]);
            hv[k] = fmaxf(fmaf(tx, w.x, fmaf(ty, w.y, w.z)), 0.0f);
        }
#pragma unroll
        for (int k = 0; k < 4; ++k) {
            const float4 w0 = *reinterpret_cast<const float4*>(&sW2[d0 + k][0]);
            const float4 w1 = *reinterpret_cast<const float4*>(&sW2[d0 + k][4]);
            const float4 w2 = *reinterpret_cast<const float4*>(&sW2[d0 + k][8]);
            const float4 w3 = *reinterpret_cast<const float4*>(&sW2[d0 + k][12]);
            acc[0]  = fmaf(hv[k], w0.x, acc[0]);   acc[1]  = fmaf(hv[k], w0.y, acc[1]);
            acc[2]  = fmaf(hv[k], w0.z, acc[2]);   acc[3]  = fmaf(hv[k], w0.w, acc[3]);
            acc[4]  = fmaf(hv[k], w1.x, acc[4]);   acc[5]  = fmaf(hv[k], w1.y, acc[5]);
            acc[6]  = fmaf(hv[k], w1.z, acc[6]);   acc[7]  = fmaf(hv[k], w1.w, acc[7]);
            acc[8]  = fmaf(hv[k], w2.x, acc[8]);   acc[9]  = fmaf(hv[k], w2.y, acc[9]);
            acc[10] = fmaf(hv[k], w2.z, acc[10]);  acc[11] = fmaf(hv[k], w2.w, acc[11]);
            acc[12] = fmaf(hv[k], w3.x, acc[12]);  acc[13] = fmaf(hv[k], w3.y, acc[13]);
            acc[14] = fmaf(hv[k], w3.z, acc[14]);  acc[15] = fmaf(hv[k], w3.w, acc[15]);
        }
    }

    if (live) {
#pragma unroll
        for (int h = 0; h < NH; ++h) {
            bias_t[(b * NH + h) * TT + t] = acc[h];
        }
    }
}

// ---------------------------------------------------------------------------
// Stage 2: out[flat] — float4 PLAIN store stream (A/B vs Round-6's
// nontemporal: only the store instruction differs from the 730.5 µs run).
// Each block owns a contiguous 41,984-element flat range (spans at most one
// plane boundary); both touchable planes are staged in LDS once per block.
// idx computed analytically: (qh-kh+23)*47 + (qw-kw+23).
// ---------------------------------------------------------------------------
#define VPT   41u                       // float4 groups per thread
#define GPB   (256u * VPT)              // groups per block
#define EPB   (GPB * 4u)                // elements per block = 41984 (< PLANE)

__global__ __launch_bounds__(256) void cpb_scatter(
    const float* __restrict__ bias_t, // (32, 16, 2209)
    float* __restrict__ out)          // (32, 16, 577, 577) flat
{
    constexpr unsigned TOTAL = (unsigned)NB * NH * PLANE; // 170,459,648 (div 4)

    const unsigned bx    = blockIdx.x;
    const unsigned tid   = threadIdx.x;
    const unsigned ebase = bx * EPB;
    if (ebase >= TOTAL) return;                 // whole block OOB (uniform)

    __shared__ float sA[TT];                    // first plane this block touches
    __shared__ float sB[TT];                    // last plane (== first if no cross)

    const unsigned eend = min(ebase + EPB, TOTAL);
    const unsigned pA   = ebase / PLANE;
    const unsigned pB   = (eend - 1u) / PLANE;  // pA or pA+1, <= 511
    const float* __restrict__ plA = bias_t + (size_t)pA * TT;
    const float* __restrict__ plB = bias_t + (size_t)pB * TT;
    for (unsigned x = tid; x < (unsigned)TT; x += 256u) {
        sA[x] = plA[x];
        sB[x] = plB[x];
    }
    __syncthreads();

#pragma unroll 2
    for (unsigned k = 0; k < VPT; ++k) {
        const unsigned off = ebase + (k * 256u + tid) * 4u;
        if (off < TOTAL) {
            const unsigned p0   = off / PLANE;          // magic-mul
            const unsigned rem0 = off - p0 * PLANE;
            float4 o;
#pragma unroll
            for (int d = 0; d < 4; ++d) {
                unsigned pp = p0;
                unsigned ee = rem0 + (unsigned)d;
                if (ee >= (unsigned)PLANE) { ee -= (unsigned)PLANE; ++pp; }
                const float* __restrict__ s = (pp == pA) ? sA : sB;
                const unsigned i = ee / NP;             // magic-mul
                const unsigned j = ee - i * NP;
                float v = 0.0f;
                if (i != 0u && j != 0u) {
                    const unsigned q  = i - 1u;
                    const unsigned kk = j - 1u;
                    const unsigned qh = q / WH,  qw = q - qh * WH;
                    const unsigned kh = kk / WH, kw = kk - kh * WH;
                    v = s[(qh - kh + (WH - 1u)) * (2u * WH - 1u)
                          + (qw - kw + (WH - 1u))];
                }
                (&o.x)[d] = v;
            }
            *reinterpret_cast<float4*>(out + off) = o;   // PLAIN store (no nt)
        }
    }
}

// ---------------------------------------------------------------------------
extern "C" void kernel_launch(void* const* d_in, const int* in_sizes, int n_in,
                              void* d_out, int out_size, void* d_ws, size_t ws_size,
                              hipStream_t stream)
{
    const float* glob_pos     = (const float*)d_in[0];
    const float* coords_table = (const float*)d_in[1];
    // d_in[2] = rpi — unused (index computed analytically in stage 2)
    const float* W1           = (const float*)d_in[3];
    const float* b1           = (const float*)d_in[4];
    const float* W2           = (const float*)d_in[5];
    // d_in[6] = num_prefix_tokens (always 1; NP/PLANE are compile-time)

    float* out    = (float*)d_out;
    float* bias_t = (float*)d_ws;   // 32*16*2209 floats = 4.5 MB scratch

    // Stage 1: 32*2209 = 70,688 threads
    const int n1 = NB * TT;
    const int blocks1 = (n1 + 255) / 256;
    cpb_mlp<<<blocks1, 256, 0, stream>>>(glob_pos, coords_table, W1, b1, W2, bias_t);

    // Stage 2: contiguous flat ranges, 41,984 elems / block
    constexpr unsigned TOTAL  = (unsigned)NB * NH * PLANE;
    const unsigned blocks2 = (TOTAL + EPB - 1u) / EPB;   // 4061
    cpb_scatter<<<blocks2, 256, 0, stream>>>(bias_t, out);
}